// Round 1
// baseline (5333.261 us; speedup 1.0000x reference)
//
#include <hip/hip_runtime.h>
#include <math.h>

// Problem constants (B,S,V,D,F,L from reference setup_inputs)
constexpr int BB = 2, SS = 512, VV = 32000, DD = 768, FF = 2048, LL = 4, HH = 12, HD = 64, FCS = 8;

__device__ __forceinline__ float softplusf(float x) {
  return fmaxf(x, 0.0f) + log1pf(expf(-fabsf(x)));
}

// ---------------- embedding gather ----------------
__global__ __launch_bounds__(256) void embed_kernel(const int* __restrict__ x, const float* __restrict__ emb,
                                                    float* __restrict__ h, int total, int D) {
  int i = blockIdx.x * 256 + threadIdx.x;
  if (i >= total) return;
  int row = i / D, d = i - row * D;
  h[i] = emb[(size_t)x[row] * D + d];
}

// ---------------- rmsnorm (one block per row) ----------------
__global__ __launch_bounds__(256) void rmsnorm_kernel(const float* __restrict__ in, const float* __restrict__ w,
                                                      float* __restrict__ out, int D) {
  int row = blockIdx.x;
  const float* xr = in + (size_t)row * D;
  float ss = 0.f;
  for (int d = threadIdx.x; d < D; d += 256) { float v = xr[d]; ss += v * v; }
  __shared__ float rbuf[256];
  rbuf[threadIdx.x] = ss; __syncthreads();
  for (int off = 128; off > 0; off >>= 1) {
    if (threadIdx.x < off) rbuf[threadIdx.x] += rbuf[threadIdx.x + off];
    __syncthreads();
  }
  float scale = rsqrtf(rbuf[0] / (float)D + 1e-5f);
  float* orow = out + (size_t)row * D;
  for (int d = threadIdx.x; d < D; d += 256) orow[d] = xr[d] * scale * w[d];
}

// ---------------- tiled f32 GEMM: C[M,N] = A[M,K] * B[N,K]^T ----------------
// EPI: 0 = store, 1 = C += val (residual add), 2 = silu(val)
template <int EPI>
__global__ __launch_bounds__(256) void gemm_nt(const float* __restrict__ A, const float* __restrict__ Bm,
                                               float* __restrict__ C, int M, int N, int K) {
  __shared__ float As[16][68];
  __shared__ float Bs[16][68];
  int bn = blockIdx.x * 64, bm = blockIdx.y * 64;
  int tid = threadIdx.x;
  int tx = tid & 15, ty = tid >> 4;
  float acc[4][4] = {};
  for (int k0 = 0; k0 < K; k0 += 16) {
#pragma unroll
    for (int i = 0; i < 4; i++) {
      int idx = tid + i * 256;
      int m = idx >> 4, kk = idx & 15;
      As[kk][m] = A[(size_t)(bm + m) * K + k0 + kk];
      Bs[kk][m] = Bm[(size_t)(bn + m) * K + k0 + kk];
    }
    __syncthreads();
#pragma unroll
    for (int kk = 0; kk < 16; kk++) {
      float4 a4 = *(const float4*)&As[kk][ty * 4];
      float4 b4 = *(const float4*)&Bs[kk][tx * 4];
      float av[4] = {a4.x, a4.y, a4.z, a4.w};
      float bv[4] = {b4.x, b4.y, b4.z, b4.w};
#pragma unroll
      for (int i = 0; i < 4; i++)
#pragma unroll
        for (int j = 0; j < 4; j++) acc[i][j] += av[i] * bv[j];
    }
    __syncthreads();
  }
#pragma unroll
  for (int i = 0; i < 4; i++) {
    int m = bm + ty * 4 + i;
#pragma unroll
    for (int j = 0; j < 4; j++) {
      int n = bn + tx * 4 + j;
      size_t off = (size_t)m * N + n;
      float v = acc[i][j];
      if (EPI == 1) C[off] += v;
      else if (EPI == 2) C[off] = v / (1.f + expf(-v));
      else C[off] = v;
    }
  }
}

// ---------------- RoPE (in place, q and k) ----------------
__global__ __launch_bounds__(256) void rope_kernel(float* __restrict__ q, float* __restrict__ k, int total) {
  int idx = blockIdx.x * 256 + threadIdx.x;
  if (idx >= total) return;
  int m = idx & 31;
  int rest = idx >> 5;           // (b*S + s)*H + h
  int h = rest % HH;
  int bs = rest / HH;            // b*S + s
  int s = bs % SS;
  float inv = expf(-9.210340371976184f * (float)m / 32.0f);  // 10000^(-m/32)
  float ang = (float)s * inv;
  float cs = cosf(ang), sn = sinf(ang);
  size_t base = (size_t)bs * DD + h * HD + 2 * m;
  float qr = q[base], qi = q[base + 1];
  q[base] = qr * cs - qi * sn;
  q[base + 1] = qr * sn + qi * cs;
  float kr = k[base], ki = k[base + 1];
  k[base] = kr * cs - ki * sn;
  k[base + 1] = kr * sn + ki * cs;
}

// ---------------- fused causal attention: one block per (b,h,sq) ----------------
__global__ __launch_bounds__(256) void attn_kernel(const float* __restrict__ q, const float* __restrict__ k,
                                                   const float* __restrict__ v, float* __restrict__ o) {
  int sq = blockIdx.x, h = blockIdx.y, b = blockIdx.z;
  int tid = threadIdx.x;
  __shared__ float qs[HD];
  __shared__ float sc[SS];
  __shared__ float rbuf[256];
  const float* qrow = q + ((size_t)b * SS + sq) * DD + h * HD;
  if (tid < HD) qs[tid] = qrow[tid];
  __syncthreads();
  for (int sk = tid; sk <= sq; sk += 256) {
    const float* krow = k + ((size_t)b * SS + sk) * DD + h * HD;
    float s = 0.f;
#pragma unroll
    for (int d = 0; d < HD; d++) s += qs[d] * krow[d];
    sc[sk] = s * 0.125f;  // 1/sqrt(64)
  }
  __syncthreads();
  float lm = -INFINITY;
  for (int sk = tid; sk <= sq; sk += 256) lm = fmaxf(lm, sc[sk]);
  rbuf[tid] = lm; __syncthreads();
  for (int off = 128; off > 0; off >>= 1) {
    if (tid < off) rbuf[tid] = fmaxf(rbuf[tid], rbuf[tid + off]);
    __syncthreads();
  }
  float mx = rbuf[0];
  __syncthreads();
  float ls = 0.f;
  for (int sk = tid; sk <= sq; sk += 256) { float e = expf(sc[sk] - mx); sc[sk] = e; ls += e; }
  rbuf[tid] = ls; __syncthreads();
  for (int off = 128; off > 0; off >>= 1) {
    if (tid < off) rbuf[tid] += rbuf[tid + off];
    __syncthreads();
  }
  float invs = 1.f / rbuf[0];
  __syncthreads();
  int d = tid & 63, part = tid >> 6;  // 4 partials per dim
  float a = 0.f;
  for (int sk = part; sk <= sq; sk += 4) a += sc[sk] * v[((size_t)b * SS + sk) * DD + h * HD + d];
  rbuf[tid] = a; __syncthreads();
  if (part == 0) {
    float val = (rbuf[d] + rbuf[64 + d] + rbuf[128 + d] + rbuf[192 + d]) * invs;
    o[((size_t)b * SS + sq) * DD + h * HD + d] = val;
  }
}

// ---------------- elementwise g *= u ----------------
__global__ __launch_bounds__(256) void mul_kernel(float* __restrict__ g, const float* __restrict__ u, int n) {
  int i = blockIdx.x * 256 + threadIdx.x;
  if (i < n) g[i] *= u[i];
}

// ---------------- context conv + softplus baseline ----------------
__global__ __launch_bounds__(256) void combine_kernel(float* __restrict__ logits, const float* __restrict__ c,
                                                      const float* __restrict__ conv_w, float* __restrict__ acc,
                                                      long total) {
  float cw = conv_w[0];
  float coef[FCS];  // coef[d] for offset d = 1..8 -> kernel[8-d] = exp(-cw*(8-d))
#pragma unroll
  for (int d = 1; d <= FCS; d++) coef[d - 1] = expf(-cw * (float)(FCS - d));
  float lsum = 0.f;
  long stride = (long)gridDim.x * 256;
  for (long idx = (long)blockIdx.x * 256 + threadIdx.x; idx < total; idx += stride) {
    float cv = c[idx];
    lsum += softplusf(cv);
    long bs = idx / VV;
    int s = (int)(bs % SS);
    float ctx = 0.f;
    int dmax = s < FCS ? s : FCS;
    for (int d = 1; d <= dmax; d++) ctx += coef[d - 1] * c[idx - (long)d * VV];
    logits[idx] += ctx;
  }
  __shared__ float rbuf[256];
  rbuf[threadIdx.x] = lsum; __syncthreads();
  for (int off = 128; off > 0; off >>= 1) {
    if (threadIdx.x < off) rbuf[threadIdx.x] += rbuf[threadIdx.x + off];
    __syncthreads();
  }
  if (threadIdx.x == 0) atomicAdd(acc + 2, rbuf[0]);
}

// ---------------- context-loss corrections (one thread per s) ----------------
__global__ __launch_bounds__(256) void corrections_kernel(const int* __restrict__ y, const float* __restrict__ c,
                                                          float* __restrict__ acc) {
  int s = blockIdx.x * 256 + threadIdx.x;
  if (s >= SS) return;
  const int YW = SS + FCS - 1;
  int w[2][FCS];
  for (int b = 0; b < 2; b++)
    for (int j = 0; j < FCS; j++) {
      int t = ((s - (FCS - 1) + j) % SS + SS) % SS;
      w[b][j] = y[b * YW + (FCS - 1) + t];
    }
  const float* c0 = c + (size_t)s * VV;
  const float* c1 = c + ((size_t)SS + s) * VV;
  float corr = 0.f;
  // target-flip: for each unique v in window, bce goes softplus(c) -> softplus(-c): delta = -c
  for (int b = 0; b < 2; b++) {
    const float* cb = b ? c1 : c0;
    for (int j = 0; j < FCS; j++) {
      int vv = w[b][j];
      bool seen = false;
      for (int p = 0; p < j; p++) if (w[b][p] == vv) { seen = true; break; }
      if (!seen) corr -= cb[vv];
    }
  }
  // duplicate-weight: cl_w = 1.5 at (s,v) where any batch has count>1; add 0.5*(bce0+bce1)
  auto cnt = [&](int b, int vv) { int n = 0; for (int j = 0; j < FCS; j++) n += (w[b][j] == vv); return n; };
  auto inw = [&](int b, int vv) { for (int j = 0; j < FCS; j++) if (w[b][j] == vv) return true; return false; };
  for (int j = 0; j < FCS; j++) {
    int vv = w[0][j];
    bool first = true;
    for (int p = 0; p < j; p++) if (w[0][p] == vv) { first = false; break; }
    if (!first) continue;
    if (cnt(0, vv) > 1 || cnt(1, vv) > 1) {
      float b0 = softplusf(-c0[vv]);                              // target=1 (vv in w0)
      float b1 = inw(1, vv) ? softplusf(-c1[vv]) : softplusf(c1[vv]);
      corr += 0.5f * (b0 + b1);
    }
  }
  for (int j = 0; j < FCS; j++) {
    int vv = w[1][j];
    bool first = true;
    for (int p = 0; p < j; p++) if (w[1][p] == vv) { first = false; break; }
    if (!first) continue;
    if (inw(0, vv)) continue;  // handled above
    if (cnt(1, vv) > 1) {
      float b0 = softplusf(c0[vv]);   // target=0 (vv not in w0)
      float b1 = softplusf(-c1[vv]);  // target=1
      corr += 0.5f * (b0 + b1);
    }
  }
  atomicAdd(acc + 2, corr);
}

// ---------------- per-row NLL (one block per (b,s)) ----------------
__global__ __launch_bounds__(256) void row_loss_kernel(const float* __restrict__ logits, const int* __restrict__ y,
                                                       float* __restrict__ acc) {
  int row = blockIdx.x;  // b*S+s
  int b = row / SS, s = row % SS;
  const float* lp = logits + (size_t)row * VV;
  __shared__ float rbuf[256];
  int tid = threadIdx.x;
  float lm = -INFINITY;
  for (int vv = tid; vv < VV; vv += 256) lm = fmaxf(lm, lp[vv]);
  rbuf[tid] = lm; __syncthreads();
  for (int off = 128; off > 0; off >>= 1) {
    if (tid < off) rbuf[tid] = fmaxf(rbuf[tid], rbuf[tid + off]);
    __syncthreads();
  }
  float mx = rbuf[0];
  __syncthreads();
  float ls = 0.f;
  for (int vv = tid; vv < VV; vv += 256) ls += expf(lp[vv] - mx);
  rbuf[tid] = ls; __syncthreads();
  for (int off = 128; off > 0; off >>= 1) {
    if (tid < off) rbuf[tid] += rbuf[tid + off];
    __syncthreads();
  }
  if (tid == 0) {
    int yt = y[b * (SS + FCS - 1) + s];
    if (yt != -1) {
      float nll = (logf(rbuf[0]) + mx) - lp[yt];
      atomicAdd(acc + 0, nll);
      atomicAdd(acc + 1, 1.0f);
    }
  }
}

__global__ void finalize_kernel(float* __restrict__ out_scalars, const float* __restrict__ acc) {
  out_scalars[0] = acc[0] / fmaxf(acc[1], 1.0f);
  out_scalars[1] = acc[2] / (float)((long)BB * SS * VV);
}

extern "C" void kernel_launch(void* const* d_in, const int* in_sizes, int n_in,
                              void* d_out, int out_size, void* d_ws, size_t ws_size,
                              hipStream_t stream) {
  const int* x = (const int*)d_in[0];
  const int* y = (const int*)d_in[1];
  const float* emb = (const float*)d_in[2];
  const float* wq = (const float*)d_in[3];
  const float* wk = (const float*)d_in[4];
  const float* wv = (const float*)d_in[5];
  const float* wo = (const float*)d_in[6];
  const float* w1 = (const float*)d_in[7];
  const float* w2 = (const float*)d_in[8];
  const float* w3 = (const float*)d_in[9];
  const float* attn_norm = (const float*)d_in[10];
  const float* ffn_norm = (const float*)d_in[11];
  const float* out_norm = (const float*)d_in[12];
  const float* w_out = (const float*)d_in[13];
  const float* w_ctx = (const float*)d_in[14];
  const float* conv_w = (const float*)d_in[15];
  float* out = (float*)d_out;

  float* ws = (float*)d_ws;
  const size_t RSZ = (size_t)BB * SS * DD;      // 786432
  const size_t FSZ = (size_t)BB * SS * FF;      // 2097152
  const size_t CSZ = (size_t)BB * SS * VV;      // 32768000
  float* h = ws;
  float* a = h + RSZ;
  float* qb = a + RSZ;
  float* kb = qb + RSZ;
  float* vb = kb + RSZ;
  float* ob = vb + RSZ;
  float* g = ob + RSZ;
  float* u = g + FSZ;
  float* c = u + FSZ;
  float* acc = c + CSZ;  // 16 floats

  hipMemsetAsync(acc, 0, 16 * sizeof(float), stream);

  const int ROWS = BB * SS;  // 1024
  // embed
  {
    int total = (int)RSZ;
    embed_kernel<<<(total + 255) / 256, 256, 0, stream>>>(x, emb, h, total, DD);
  }
  for (int l = 0; l < LL; l++) {
    const float* wq_l = wq + (size_t)l * DD * DD;
    const float* wk_l = wk + (size_t)l * DD * DD;
    const float* wv_l = wv + (size_t)l * DD * DD;
    const float* wo_l = wo + (size_t)l * DD * DD;
    const float* w1_l = w1 + (size_t)l * FF * DD;
    const float* w2_l = w2 + (size_t)l * DD * FF;
    const float* w3_l = w3 + (size_t)l * FF * DD;

    rmsnorm_kernel<<<ROWS, 256, 0, stream>>>(h, attn_norm + l * DD, a, DD);
    dim3 gqkv(DD / 64, ROWS / 64);
    gemm_nt<0><<<gqkv, 256, 0, stream>>>(a, wq_l, qb, ROWS, DD, DD);
    gemm_nt<0><<<gqkv, 256, 0, stream>>>(a, wk_l, kb, ROWS, DD, DD);
    gemm_nt<0><<<gqkv, 256, 0, stream>>>(a, wv_l, vb, ROWS, DD, DD);
    int rope_total = BB * SS * HH * 32;
    rope_kernel<<<(rope_total + 255) / 256, 256, 0, stream>>>(qb, kb, rope_total);
    attn_kernel<<<dim3(SS, HH, BB), 256, 0, stream>>>(qb, kb, vb, ob);
    gemm_nt<1><<<gqkv, 256, 0, stream>>>(ob, wo_l, h, ROWS, DD, DD);  // h += o @ wo^T

    rmsnorm_kernel<<<ROWS, 256, 0, stream>>>(h, ffn_norm + l * DD, a, DD);
    dim3 gffn(FF / 64, ROWS / 64);
    gemm_nt<2><<<gffn, 256, 0, stream>>>(a, w1_l, g, ROWS, FF, DD);  // silu(a@w1^T)
    gemm_nt<0><<<gffn, 256, 0, stream>>>(a, w3_l, u, ROWS, FF, DD);
    mul_kernel<<<((int)FSZ + 255) / 256, 256, 0, stream>>>(g, u, (int)FSZ);
    gemm_nt<1><<<gqkv, 256, 0, stream>>>(g, w2_l, h, ROWS, DD, FF);  // h += gu @ w2^T
  }
  // final norm + heads
  rmsnorm_kernel<<<ROWS, 256, 0, stream>>>(h, out_norm, a, DD);
  dim3 ghead(VV / 64, ROWS / 64);
  gemm_nt<0><<<ghead, 256, 0, stream>>>(a, w_out, out, ROWS, VV, DD);
  gemm_nt<0><<<ghead, 256, 0, stream>>>(a, w_ctx, c, ROWS, VV, DD);

  combine_kernel<<<16384, 256, 0, stream>>>(out, c, conv_w, acc, (long)CSZ);
  corrections_kernel<<<2, 256, 0, stream>>>(y, c, acc);
  row_loss_kernel<<<ROWS, 256, 0, stream>>>(out, y, acc);
  finalize_kernel<<<1, 1, 0, stream>>>(out + CSZ, acc);
}

// Round 2
// 3019.849 us; speedup vs baseline: 1.7661x; 1.7661x over previous
//
#include <hip/hip_runtime.h>
#include <math.h>

// Problem constants (B,S,V,D,F,L from reference setup_inputs)
constexpr int BB = 2, SS = 512, VV = 32000, DD = 768, FF = 2048, LL = 4, HH = 12, HD = 64, FCS = 8;
constexpr int QS = 2304;  // fused qkv row stride

typedef short v8s __attribute__((ext_vector_type(8)));
typedef float v4f __attribute__((ext_vector_type(4)));

__device__ __forceinline__ float softplusf(float x) {
  return fmaxf(x, 0.0f) + log1pf(expf(-fabsf(x)));
}

__device__ __forceinline__ unsigned short f2bf(float f) {
  unsigned int u = __float_as_uint(f);
  unsigned int rounding = 0x7fff + ((u >> 16) & 1);
  return (unsigned short)((u + rounding) >> 16);
}

// ---------------- f32 -> bf16 conversion (4 elements/thread) ----------------
__global__ __launch_bounds__(256) void cvt4_kernel(const float* __restrict__ in, unsigned short* __restrict__ out,
                                                   long n) {
  long i = ((long)blockIdx.x * 256 + threadIdx.x) * 4;
  if (i >= n) return;
  float4 v = *(const float4*)(in + i);
  ushort4 o;
  o.x = f2bf(v.x); o.y = f2bf(v.y); o.z = f2bf(v.z); o.w = f2bf(v.w);
  *(ushort4*)(out + i) = o;
}

// ---------------- embedding gather ----------------
__global__ __launch_bounds__(256) void embed_kernel(const int* __restrict__ x, const float* __restrict__ emb,
                                                    float* __restrict__ h, int total, int D) {
  int i = blockIdx.x * 256 + threadIdx.x;
  if (i >= total) return;
  int row = i / D, d = i - row * D;
  h[i] = emb[(size_t)x[row] * D + d];
}

// ---------------- rmsnorm (one block per row), writes bf16 ----------------
__global__ __launch_bounds__(256) void rmsnorm_kernel(const float* __restrict__ in, const float* __restrict__ w,
                                                      unsigned short* __restrict__ out, int D) {
  int row = blockIdx.x;
  const float* xr = in + (size_t)row * D;
  float ss = 0.f;
  for (int d = threadIdx.x; d < D; d += 256) { float v = xr[d]; ss += v * v; }
  __shared__ float rbuf[256];
  rbuf[threadIdx.x] = ss; __syncthreads();
  for (int off = 128; off > 0; off >>= 1) {
    if (threadIdx.x < off) rbuf[threadIdx.x] += rbuf[threadIdx.x + off];
    __syncthreads();
  }
  float scale = rsqrtf(rbuf[0] / (float)D + 1e-5f);
  unsigned short* orow = out + (size_t)row * D;
  for (int d = threadIdx.x; d < D; d += 256) orow[d] = f2bf(xr[d] * scale * w[d]);
}

// ---------------- bf16 MFMA GEMM: C[M,N] (f32) = A[M,K] * B[N,K]^T (bf16) ----------------
// 128x128 tile, BK=64, 4 waves in 2x2, each wave 64x64 via 16x16x32 MFMA.
// LDS layout: element (r, c) at r*64 + ((c/8) ^ (r&7))*8 + c%8  (16B-slot XOR swizzle).
// Staged with global_load_lds(16): wave-uniform LDS base + lane*16.
// EPI: 0 = store, 1 = C += val (residual add)
template <int EPI>
__global__ __launch_bounds__(256) void gemm_bf16(const unsigned short* __restrict__ A,
                                                 const unsigned short* __restrict__ B,
                                                 float* __restrict__ C, int M, int N, int K) {
  __shared__ __align__(16) unsigned short As[128 * 64];
  __shared__ __align__(16) unsigned short Bs[128 * 64];
  const int tid = threadIdx.x;
  const int wave = tid >> 6, lane = tid & 63;
  const int bm = blockIdx.y * 128, bn = blockIdx.x * 128;
  const int wr = (wave >> 1) * 64, wc = (wave & 1) * 64;
  const int lrow = lane >> 3;   // row within 8-row staging group
  const int lslot = lane & 7;   // physical 16B slot within row
  const int quad = lane >> 4, col = lane & 15;

  v4f acc[4][4] = {};

  for (int k0 = 0; k0 < K; k0 += 64) {
#pragma unroll
    for (int i = 0; i < 4; i++) {
      int j = wave * 4 + i;          // staging group 0..15 (8 rows each)
      int r = j * 8 + lrow;          // tile row 0..127
      int g = lslot ^ lrow;          // logical col-group this lane fetches
      const unsigned short* ga = A + (size_t)(bm + r) * K + k0 + g * 8;
      const unsigned short* gb = B + (size_t)(bn + r) * K + k0 + g * 8;
      __builtin_amdgcn_global_load_lds((const __attribute__((address_space(1))) void*)ga,
                                       (__attribute__((address_space(3))) void*)(As + j * 512), 16, 0, 0);
      __builtin_amdgcn_global_load_lds((const __attribute__((address_space(1))) void*)gb,
                                       (__attribute__((address_space(3))) void*)(Bs + j * 512), 16, 0, 0);
    }
    __syncthreads();
#pragma unroll
    for (int kk = 0; kk < 2; kk++) {
      int g = kk * 4 + quad;  // col-group 0..7
      v8s af[4], bfr[4];
#pragma unroll
      for (int i = 0; i < 4; i++) {
        int m = wr + i * 16 + col;
        af[i] = *(const v8s*)(As + m * 64 + ((g ^ (m & 7)) * 8));
        int n = wc + i * 16 + col;
        bfr[i] = *(const v8s*)(Bs + n * 64 + ((g ^ (n & 7)) * 8));
      }
#pragma unroll
      for (int i = 0; i < 4; i++)
#pragma unroll
        for (int jj = 0; jj < 4; jj++)
          acc[i][jj] = __builtin_amdgcn_mfma_f32_16x16x32_bf16(af[i], bfr[jj], acc[i][jj], 0, 0, 0);
    }
    __syncthreads();
  }
  // epilogue: C/D layout col=lane&15, row=quad*4+reg
#pragma unroll
  for (int i = 0; i < 4; i++) {
#pragma unroll
    for (int jj = 0; jj < 4; jj++) {
#pragma unroll
      for (int r = 0; r < 4; r++) {
        int row = bm + wr + i * 16 + quad * 4 + r;
        int ncol = bn + wc + jj * 16 + col;
        size_t off = (size_t)row * N + ncol;
        float v = acc[i][jj][r];
        if (EPI == 1) C[off] += v;
        else C[off] = v;
      }
    }
  }
}

// ---------------- RoPE (in place on fused qkv, stride QS) ----------------
__global__ __launch_bounds__(256) void rope_kernel(float* __restrict__ qkv, int total) {
  int idx = blockIdx.x * 256 + threadIdx.x;
  if (idx >= total) return;
  int m = idx & 31;
  int rest = idx >> 5;           // (b*S + s)*H + h
  int h = rest % HH;
  int bs = rest / HH;            // b*S + s
  int s = bs % SS;
  float inv = expf(-9.210340371976184f * (float)m / 32.0f);  // 10000^(-m/32)
  float ang = (float)s * inv;
  float cs = cosf(ang), sn = sinf(ang);
  size_t base = (size_t)bs * QS + h * HD + 2 * m;
  float qr = qkv[base], qi = qkv[base + 1];
  qkv[base] = qr * cs - qi * sn;
  qkv[base + 1] = qr * sn + qi * cs;
  size_t kbase = base + DD;
  float kr = qkv[kbase], ki = qkv[kbase + 1];
  qkv[kbase] = kr * cs - ki * sn;
  qkv[kbase + 1] = kr * sn + ki * cs;
}

// ---------------- fused causal attention: one block per (b,h,sq); bf16 out ----------------
__global__ __launch_bounds__(256) void attn_kernel(const float* __restrict__ qkv, unsigned short* __restrict__ o) {
  int sq = blockIdx.x, h = blockIdx.y, b = blockIdx.z;
  int tid = threadIdx.x;
  __shared__ __align__(16) float qs[HD];
  __shared__ float sc[SS];
  __shared__ float rbuf[256];
  const float* qrow = qkv + ((size_t)b * SS + sq) * QS + h * HD;
  if (tid < HD) qs[tid] = qrow[tid];
  __syncthreads();
  for (int sk = tid; sk <= sq; sk += 256) {
    const float4* k4 = (const float4*)(qkv + ((size_t)b * SS + sk) * QS + DD + h * HD);
    float s = 0.f;
#pragma unroll
    for (int d4 = 0; d4 < 16; d4++) {
      float4 kv = k4[d4];
      float4 qv = *(const float4*)&qs[d4 * 4];
      s += qv.x * kv.x + qv.y * kv.y + qv.z * kv.z + qv.w * kv.w;
    }
    sc[sk] = s * 0.125f;  // 1/sqrt(64)
  }
  __syncthreads();
  float lm = -INFINITY;
  for (int sk = tid; sk <= sq; sk += 256) lm = fmaxf(lm, sc[sk]);
  rbuf[tid] = lm; __syncthreads();
  for (int off = 128; off > 0; off >>= 1) {
    if (tid < off) rbuf[tid] = fmaxf(rbuf[tid], rbuf[tid + off]);
    __syncthreads();
  }
  float mx = rbuf[0];
  __syncthreads();
  float ls = 0.f;
  for (int sk = tid; sk <= sq; sk += 256) { float e = expf(sc[sk] - mx); sc[sk] = e; ls += e; }
  rbuf[tid] = ls; __syncthreads();
  for (int off = 128; off > 0; off >>= 1) {
    if (tid < off) rbuf[tid] += rbuf[tid + off];
    __syncthreads();
  }
  float invs = 1.f / rbuf[0];
  __syncthreads();
  int d = tid & 63, part = tid >> 6;  // 4 partials per dim
  float a = 0.f;
  for (int sk = part; sk <= sq; sk += 4)
    a += sc[sk] * qkv[((size_t)b * SS + sk) * QS + 2 * DD + h * HD + d];
  rbuf[tid] = a; __syncthreads();
  if (part == 0) {
    float val = (rbuf[d] + rbuf[64 + d] + rbuf[128 + d] + rbuf[192 + d]) * invs;
    o[((size_t)b * SS + sq) * DD + h * HD + d] = f2bf(val);
  }
}

// ---------------- silu(gate)*up from fused [1024][4096] f32, writes bf16 [1024][2048] ----------------
__global__ __launch_bounds__(256) void silu_mul_kernel(const float* __restrict__ gu, unsigned short* __restrict__ out,
                                                       int n) {
  int i = blockIdx.x * 256 + threadIdx.x;
  if (i >= n) return;
  int m = i >> 11, j = i & 2047;
  float g = gu[(size_t)m * 4096 + j];
  float u = gu[(size_t)m * 4096 + 2048 + j];
  float s = g / (1.f + expf(-g));
  out[i] = f2bf(s * u);
}

// ---------------- context conv + softplus baseline ----------------
__global__ __launch_bounds__(256) void combine_kernel(float* __restrict__ logits, const float* __restrict__ c,
                                                      const float* __restrict__ conv_w, float* __restrict__ acc,
                                                      long total) {
  float cw = conv_w[0];
  float coef[FCS];  // coef[d-1] for offset d = 1..8 -> kernel[8-d] = exp(-cw*(8-d))
#pragma unroll
  for (int d = 1; d <= FCS; d++) coef[d - 1] = expf(-cw * (float)(FCS - d));
  float lsum = 0.f;
  long stride = (long)gridDim.x * 256;
  for (long idx = (long)blockIdx.x * 256 + threadIdx.x; idx < total; idx += stride) {
    float cv = c[idx];
    lsum += softplusf(cv);
    long bs = idx / VV;
    int s = (int)(bs % SS);
    float ctx = 0.f;
    int dmax = s < FCS ? s : FCS;
    for (int d = 1; d <= dmax; d++) ctx += coef[d - 1] * c[idx - (long)d * VV];
    logits[idx] += ctx;
  }
  __shared__ float rbuf[256];
  rbuf[threadIdx.x] = lsum; __syncthreads();
  for (int off = 128; off > 0; off >>= 1) {
    if (threadIdx.x < off) rbuf[threadIdx.x] += rbuf[threadIdx.x + off];
    __syncthreads();
  }
  if (threadIdx.x == 0) atomicAdd(acc + 2, rbuf[0]);
}

// ---------------- context-loss corrections (one thread per s) ----------------
__global__ __launch_bounds__(256) void corrections_kernel(const int* __restrict__ y, const float* __restrict__ c,
                                                          float* __restrict__ acc) {
  int s = blockIdx.x * 256 + threadIdx.x;
  if (s >= SS) return;
  const int YW = SS + FCS - 1;
  int w[2][FCS];
  for (int b = 0; b < 2; b++)
    for (int j = 0; j < FCS; j++) {
      int t = ((s - (FCS - 1) + j) % SS + SS) % SS;
      w[b][j] = y[b * YW + (FCS - 1) + t];
    }
  const float* c0 = c + (size_t)s * VV;
  const float* c1 = c + ((size_t)SS + s) * VV;
  float corr = 0.f;
  for (int b = 0; b < 2; b++) {
    const float* cb = b ? c1 : c0;
    for (int j = 0; j < FCS; j++) {
      int vv = w[b][j];
      bool seen = false;
      for (int p = 0; p < j; p++) if (w[b][p] == vv) { seen = true; break; }
      if (!seen) corr -= cb[vv];
    }
  }
  auto cnt = [&](int b, int vv) { int n = 0; for (int j = 0; j < FCS; j++) n += (w[b][j] == vv); return n; };
  auto inw = [&](int b, int vv) { for (int j = 0; j < FCS; j++) if (w[b][j] == vv) return true; return false; };
  for (int j = 0; j < FCS; j++) {
    int vv = w[0][j];
    bool first = true;
    for (int p = 0; p < j; p++) if (w[0][p] == vv) { first = false; break; }
    if (!first) continue;
    if (cnt(0, vv) > 1 || cnt(1, vv) > 1) {
      float b0 = softplusf(-c0[vv]);
      float b1 = inw(1, vv) ? softplusf(-c1[vv]) : softplusf(c1[vv]);
      corr += 0.5f * (b0 + b1);
    }
  }
  for (int j = 0; j < FCS; j++) {
    int vv = w[1][j];
    bool first = true;
    for (int p = 0; p < j; p++) if (w[1][p] == vv) { first = false; break; }
    if (!first) continue;
    if (inw(0, vv)) continue;
    if (cnt(1, vv) > 1) {
      float b0 = softplusf(c0[vv]);
      float b1 = softplusf(-c1[vv]);
      corr += 0.5f * (b0 + b1);
    }
  }
  atomicAdd(acc + 2, corr);
}

// ---------------- per-row NLL (one block per (b,s)) ----------------
__global__ __launch_bounds__(256) void row_loss_kernel(const float* __restrict__ logits, const int* __restrict__ y,
                                                       float* __restrict__ acc) {
  int row = blockIdx.x;  // b*S+s
  int b = row / SS, s = row % SS;
  const float* lp = logits + (size_t)row * VV;
  __shared__ float rbuf[256];
  int tid = threadIdx.x;
  float lm = -INFINITY;
  for (int vv = tid; vv < VV; vv += 256) lm = fmaxf(lm, lp[vv]);
  rbuf[tid] = lm; __syncthreads();
  for (int off = 128; off > 0; off >>= 1) {
    if (tid < off) rbuf[tid] = fmaxf(rbuf[tid], rbuf[tid + off]);
    __syncthreads();
  }
  float mx = rbuf[0];
  __syncthreads();
  float ls = 0.f;
  for (int vv = tid; vv < VV; vv += 256) ls += expf(lp[vv] - mx);
  rbuf[tid] = ls; __syncthreads();
  for (int off = 128; off > 0; off >>= 1) {
    if (tid < off) rbuf[tid] += rbuf[tid + off];
    __syncthreads();
  }
  if (tid == 0) {
    int yt = y[b * (SS + FCS - 1) + s];
    if (yt != -1) {
      float nll = (logf(rbuf[0]) + mx) - lp[yt];
      atomicAdd(acc + 0, nll);
      atomicAdd(acc + 1, 1.0f);
    }
  }
}

__global__ void finalize_kernel(float* __restrict__ out_scalars, const float* __restrict__ acc) {
  out_scalars[0] = acc[0] / fmaxf(acc[1], 1.0f);
  out_scalars[1] = acc[2] / (float)((long)BB * SS * VV);
}

extern "C" void kernel_launch(void* const* d_in, const int* in_sizes, int n_in,
                              void* d_out, int out_size, void* d_ws, size_t ws_size,
                              hipStream_t stream) {
  const int* x = (const int*)d_in[0];
  const int* y = (const int*)d_in[1];
  const float* emb = (const float*)d_in[2];
  const float* wq = (const float*)d_in[3];
  const float* wk = (const float*)d_in[4];
  const float* wv = (const float*)d_in[5];
  const float* wo = (const float*)d_in[6];
  const float* w1 = (const float*)d_in[7];
  const float* w2 = (const float*)d_in[8];
  const float* w3 = (const float*)d_in[9];
  const float* attn_norm = (const float*)d_in[10];
  const float* ffn_norm = (const float*)d_in[11];
  const float* out_norm = (const float*)d_in[12];
  const float* w_out = (const float*)d_in[13];
  const float* w_ctx = (const float*)d_in[14];
  const float* conv_w = (const float*)d_in[15];
  float* out = (float*)d_out;

  // ---- workspace carve (bytes, 256-aligned) ----
  char* ws = (char*)d_ws;
  size_t off = 0;
  auto carve = [&](size_t bytes) { char* p = ws + off; off += (bytes + 255) & ~(size_t)255; return p; };
  float* h    = (float*)carve((size_t)BB * SS * DD * 4);        // 3.1 MB
  float* qkv  = (float*)carve((size_t)BB * SS * QS * 4);        // 9.4 MB
  float* gu   = (float*)carve((size_t)BB * SS * 4096 * 4);      // 16.8 MB
  unsigned short* a16  = (unsigned short*)carve((size_t)BB * SS * DD * 2);
  unsigned short* ob16 = (unsigned short*)carve((size_t)BB * SS * DD * 2);
  unsigned short* gu16 = (unsigned short*)carve((size_t)BB * SS * FF * 2);
  float* c    = (float*)carve((size_t)BB * SS * VV * 4);        // 131 MB
  unsigned short* wbuf = (unsigned short*)carve((size_t)LL * (QS * DD + 4096 * DD + DD * DD + DD * FF) * 2);  // 56.6 MB
  float* acc  = (float*)carve(64);

  unsigned short* wqkv16 = wbuf;                                    // [L][2304][768]
  unsigned short* w1316  = wqkv16 + (size_t)LL * QS * DD;           // [L][4096][768]
  unsigned short* wo16   = w1316 + (size_t)LL * 4096 * DD;          // [L][768][768]
  unsigned short* w216   = wo16 + (size_t)LL * DD * DD;             // [L][768][2048]
  unsigned short* whead16 = wbuf;                                   // reused for w_out / w_ctx (49.2 MB <= 56.6)

  hipMemsetAsync(acc, 0, 16 * sizeof(float), stream);

  const int ROWS = BB * SS;  // 1024
  const long DD2 = (long)DD * DD, FD = (long)FF * DD;
  auto cvtgrid = [](long n) { return (int)((n / 4 + 255) / 256); };

  // ---- convert layer weights to bf16 (fused layouts) ----
  for (int l = 0; l < LL; l++) {
    cvt4_kernel<<<cvtgrid(DD2), 256, 0, stream>>>(wq + l * DD2, wqkv16 + (size_t)l * QS * DD + 0 * DD2, DD2);
    cvt4_kernel<<<cvtgrid(DD2), 256, 0, stream>>>(wk + l * DD2, wqkv16 + (size_t)l * QS * DD + 1 * DD2, DD2);
    cvt4_kernel<<<cvtgrid(DD2), 256, 0, stream>>>(wv + l * DD2, wqkv16 + (size_t)l * QS * DD + 2 * DD2, DD2);
    cvt4_kernel<<<cvtgrid(FD), 256, 0, stream>>>(w1 + l * FD, w1316 + (size_t)l * 4096 * DD, FD);
    cvt4_kernel<<<cvtgrid(FD), 256, 0, stream>>>(w3 + l * FD, w1316 + (size_t)l * 4096 * DD + (size_t)2048 * DD, FD);
    cvt4_kernel<<<cvtgrid(DD2), 256, 0, stream>>>(wo + l * DD2, wo16 + (size_t)l * DD2, DD2);
    cvt4_kernel<<<cvtgrid(FD), 256, 0, stream>>>(w2 + l * FD, w216 + (size_t)l * FD, FD);
  }

  // ---- embed ----
  embed_kernel<<<((int)(BB * SS * DD) + 255) / 256, 256, 0, stream>>>(x, emb, h, BB * SS * DD, DD);

  // ---- layers ----
  for (int l = 0; l < LL; l++) {
    rmsnorm_kernel<<<ROWS, 256, 0, stream>>>(h, attn_norm + l * DD, a16, DD);
    gemm_bf16<0><<<dim3(QS / 128, ROWS / 128), 256, 0, stream>>>(a16, wqkv16 + (size_t)l * QS * DD, qkv, ROWS, QS, DD);
    int rope_total = BB * SS * HH * 32;
    rope_kernel<<<(rope_total + 255) / 256, 256, 0, stream>>>(qkv, rope_total);
    attn_kernel<<<dim3(SS, HH, BB), 256, 0, stream>>>(qkv, ob16);
    gemm_bf16<1><<<dim3(DD / 128, ROWS / 128), 256, 0, stream>>>(ob16, wo16 + (size_t)l * DD2, h, ROWS, DD, DD);

    rmsnorm_kernel<<<ROWS, 256, 0, stream>>>(h, ffn_norm + l * DD, a16, DD);
    gemm_bf16<0><<<dim3(4096 / 128, ROWS / 128), 256, 0, stream>>>(a16, w1316 + (size_t)l * 4096 * DD, gu, ROWS, 4096, DD);
    silu_mul_kernel<<<(ROWS * FF + 255) / 256, 256, 0, stream>>>(gu, gu16, ROWS * FF);
    gemm_bf16<1><<<dim3(DD / 128, ROWS / 128), 256, 0, stream>>>(gu16, w216 + (size_t)l * FD, h, ROWS, DD, FF);
  }

  // ---- final norm + heads (lazy head-weight conversion into reused wbuf) ----
  rmsnorm_kernel<<<ROWS, 256, 0, stream>>>(h, out_norm, a16, DD);
  const long HV = (long)VV * DD;
  cvt4_kernel<<<cvtgrid(HV), 256, 0, stream>>>(w_out, whead16, HV);
  gemm_bf16<0><<<dim3(VV / 128, ROWS / 128), 256, 0, stream>>>(a16, whead16, out, ROWS, VV, DD);
  cvt4_kernel<<<cvtgrid(HV), 256, 0, stream>>>(w_ctx, whead16, HV);
  gemm_bf16<0><<<dim3(VV / 128, ROWS / 128), 256, 0, stream>>>(a16, whead16, c, ROWS, VV, DD);

  // ---- losses ----
  const long CSZ = (long)BB * SS * VV;
  combine_kernel<<<16384, 256, 0, stream>>>(out, c, conv_w, acc, CSZ);
  corrections_kernel<<<2, 256, 0, stream>>>(y, c, acc);
  row_loss_kernel<<<ROWS, 256, 0, stream>>>(out, y, acc);
  finalize_kernel<<<1, 1, 0, stream>>>(out + CSZ, acc);
}

// Round 3
// 1688.043 us; speedup vs baseline: 3.1594x; 1.7890x over previous
//
#include <hip/hip_runtime.h>
#include <math.h>

// Problem constants (B,S,V,D,F,L from reference setup_inputs)
constexpr int BB = 2, SS = 512, VV = 32000, DD = 768, FF = 2048, LL = 4, HH = 12, HD = 64, FCS = 8;
constexpr int QS = 2304;  // fused qkv row stride

typedef short v8s __attribute__((ext_vector_type(8)));
typedef float v4f __attribute__((ext_vector_type(4)));

__device__ __forceinline__ float softplusf(float x) {
  return fmaxf(x, 0.0f) + log1pf(expf(-fabsf(x)));
}

__device__ __forceinline__ unsigned short f2bf(float f) {
  unsigned int u = __float_as_uint(f);
  unsigned int rounding = 0x7fff + ((u >> 16) & 1);
  return (unsigned short)((u + rounding) >> 16);
}

// ---------------- f32 -> bf16 conversion (4 elements/thread) ----------------
__global__ __launch_bounds__(256) void cvt4_kernel(const float* __restrict__ in, unsigned short* __restrict__ out,
                                                   long n) {
  long i = ((long)blockIdx.x * 256 + threadIdx.x) * 4;
  if (i >= n) return;
  float4 v = *(const float4*)(in + i);
  ushort4 o;
  o.x = f2bf(v.x); o.y = f2bf(v.y); o.z = f2bf(v.z); o.w = f2bf(v.w);
  *(ushort4*)(out + i) = o;
}

// ---------------- embedding gather ----------------
__global__ __launch_bounds__(256) void embed_kernel(const int* __restrict__ x, const float* __restrict__ emb,
                                                    float* __restrict__ h, int total, int D) {
  int i = blockIdx.x * 256 + threadIdx.x;
  if (i >= total) return;
  int row = i / D, d = i - row * D;
  h[i] = emb[(size_t)x[row] * D + d];
}

// ---------------- rmsnorm (one block per row), writes bf16 ----------------
__global__ __launch_bounds__(256) void rmsnorm_kernel(const float* __restrict__ in, const float* __restrict__ w,
                                                      unsigned short* __restrict__ out, int D) {
  int row = blockIdx.x;
  const float* xr = in + (size_t)row * D;
  float ss = 0.f;
  for (int d = threadIdx.x; d < D; d += 256) { float v = xr[d]; ss += v * v; }
  __shared__ float rbuf[256];
  rbuf[threadIdx.x] = ss; __syncthreads();
  for (int off = 128; off > 0; off >>= 1) {
    if (threadIdx.x < off) rbuf[threadIdx.x] += rbuf[threadIdx.x + off];
    __syncthreads();
  }
  float scale = rsqrtf(rbuf[0] / (float)D + 1e-5f);
  unsigned short* orow = out + (size_t)row * D;
  for (int d = threadIdx.x; d < D; d += 256) orow[d] = f2bf(xr[d] * scale * w[d]);
}

// ---------------- bf16 MFMA GEMM: C[M,N] (f32) = A[M,K] * B[N,K]^T (bf16) ----------------
// 128x128 tile, BK=64, 4 waves in 2x2, each wave 64x64 via 16x16x32 MFMA.
// LDS layout: element (r, c) at r*64 + ((c/8) ^ (r&7))*8 + c%8  (16B-slot XOR swizzle).
// EPI: 0 = store, 1 = C += val (residual add)
template <int EPI>
__global__ __launch_bounds__(256) void gemm_bf16(const unsigned short* __restrict__ A,
                                                 const unsigned short* __restrict__ B,
                                                 float* __restrict__ C, int M, int N, int K) {
  __shared__ __align__(16) unsigned short As[128 * 64];
  __shared__ __align__(16) unsigned short Bs[128 * 64];
  const int tid = threadIdx.x;
  const int wave = tid >> 6, lane = tid & 63;
  const int bm = blockIdx.y * 128, bn = blockIdx.x * 128;
  const int wr = (wave >> 1) * 64, wc = (wave & 1) * 64;
  const int lrow = lane >> 3;   // row within 8-row staging group
  const int lslot = lane & 7;   // physical 16B slot within row
  const int quad = lane >> 4, col = lane & 15;

  v4f acc[4][4] = {};

  for (int k0 = 0; k0 < K; k0 += 64) {
#pragma unroll
    for (int i = 0; i < 4; i++) {
      int j = wave * 4 + i;          // staging group 0..15 (8 rows each)
      int r = j * 8 + lrow;          // tile row 0..127
      int g = lslot ^ lrow;          // logical col-group this lane fetches
      const unsigned short* ga = A + (size_t)(bm + r) * K + k0 + g * 8;
      const unsigned short* gb = B + (size_t)(bn + r) * K + k0 + g * 8;
      __builtin_amdgcn_global_load_lds((const __attribute__((address_space(1))) void*)ga,
                                       (__attribute__((address_space(3))) void*)(As + j * 512), 16, 0, 0);
      __builtin_amdgcn_global_load_lds((const __attribute__((address_space(1))) void*)gb,
                                       (__attribute__((address_space(3))) void*)(Bs + j * 512), 16, 0, 0);
    }
    __syncthreads();
#pragma unroll
    for (int kk = 0; kk < 2; kk++) {
      int g = kk * 4 + quad;  // col-group 0..7
      v8s af[4], bfr[4];
#pragma unroll
      for (int i = 0; i < 4; i++) {
        int m = wr + i * 16 + col;
        af[i] = *(const v8s*)(As + m * 64 + ((g ^ (m & 7)) * 8));
        int n = wc + i * 16 + col;
        bfr[i] = *(const v8s*)(Bs + n * 64 + ((g ^ (n & 7)) * 8));
      }
#pragma unroll
      for (int i = 0; i < 4; i++)
#pragma unroll
        for (int jj = 0; jj < 4; jj++)
          acc[i][jj] = __builtin_amdgcn_mfma_f32_16x16x32_bf16(af[i], bfr[jj], acc[i][jj], 0, 0, 0);
    }
    __syncthreads();
  }
  // epilogue: C/D layout col=lane&15, row=quad*4+reg
#pragma unroll
  for (int i = 0; i < 4; i++) {
#pragma unroll
    for (int jj = 0; jj < 4; jj++) {
#pragma unroll
      for (int r = 0; r < 4; r++) {
        int row = bm + wr + i * 16 + quad * 4 + r;
        int ncol = bn + wc + jj * 16 + col;
        size_t off = (size_t)row * N + ncol;
        float v = acc[i][jj][r];
        if (EPI == 1) C[off] += v;
        else C[off] = v;
      }
    }
  }
}

// ---------------- RoPE (in place on fused qkv, stride QS) ----------------
__global__ __launch_bounds__(256) void rope_kernel(float* __restrict__ qkv, int total) {
  int idx = blockIdx.x * 256 + threadIdx.x;
  if (idx >= total) return;
  int m = idx & 31;
  int rest = idx >> 5;           // (b*S + s)*H + h
  int h = rest % HH;
  int bs = rest / HH;            // b*S + s
  int s = bs % SS;
  float inv = expf(-9.210340371976184f * (float)m / 32.0f);  // 10000^(-m/32)
  float ang = (float)s * inv;
  float cs = cosf(ang), sn = sinf(ang);
  size_t base = (size_t)bs * QS + h * HD + 2 * m;
  float qr = qkv[base], qi = qkv[base + 1];
  qkv[base] = qr * cs - qi * sn;
  qkv[base + 1] = qr * sn + qi * cs;
  size_t kbase = base + DD;
  float kr = qkv[kbase], ki = qkv[kbase + 1];
  qkv[kbase] = kr * cs - ki * sn;
  qkv[kbase + 1] = kr * sn + ki * cs;
}

// ---------------- flash MFMA attention ----------------
// Block = (b, h, 64-query tile); 4 waves x 16 queries. K rows (XOR-swizzled) and
// V^T (padded stride) staged bf16 in LDS. Per 32-key block: 4 S-MFMAs, online
// softmax (16-lane shuffle reduces), P via per-wave LDS (C-layout -> A-layout),
// 4 PV-MFMAs. Q pre-scaled by 1/sqrt(HD) at load.
__global__ __launch_bounds__(256) void attn_mfma_kernel(const float* __restrict__ qkv,
                                                        unsigned short* __restrict__ o) {
  constexpr int VSTR = 520;  // Vt row stride in shorts (1040 B: 16B-aligned, bank-spread)
  constexpr int PSTR = 40;   // P row stride in shorts (80 B: 16B-aligned)
  __shared__ __align__(16) unsigned short Ks[512 * 64];
  __shared__ __align__(16) unsigned short Vt[64 * VSTR];
  __shared__ __align__(16) unsigned short Ps[4 * 16 * PSTR];
  const int tid = threadIdx.x;
  const int qbase = blockIdx.x * 64, h = blockIdx.y, b = blockIdx.z;
  const int nk = qbase + 64;  // keys 0..nk-1 needed (causal)
  // ---- stage K (swizzled rows) and V^T ----
  {
    const int group = tid >> 4, pos = tid & 15;
    for (int r = group; r < nk; r += 16) {
      const float* kp = qkv + ((size_t)b * SS + r) * QS + DD + h * HD + pos * 4;
      float4 kv = *(const float4*)kp;
      ushort4 kbv;
      kbv.x = f2bf(kv.x); kbv.y = f2bf(kv.y); kbv.z = f2bf(kv.z); kbv.w = f2bf(kv.w);
      int slot = (pos >> 1) ^ (r & 7);
      *(ushort4*)(Ks + r * 64 + slot * 8 + (pos & 1) * 4) = kbv;
      const float* vp = kp + DD;
      float4 vv = *(const float4*)vp;
      Vt[(pos * 4 + 0) * VSTR + r] = f2bf(vv.x);
      Vt[(pos * 4 + 1) * VSTR + r] = f2bf(vv.y);
      Vt[(pos * 4 + 2) * VSTR + r] = f2bf(vv.z);
      Vt[(pos * 4 + 3) * VSTR + r] = f2bf(vv.w);
    }
  }
  __syncthreads();
  const int wave = tid >> 6, lane = tid & 63;
  const int quad = lane >> 4, col = lane & 15;
  const int q0 = qbase + wave * 16;  // this wave's 16 queries
  unsigned short* Pw = Ps + wave * 16 * PSTR;
  // ---- Q A-fragments (scaled by 1/8) ----
  v8s aq[2];
  {
    const float* qp = qkv + ((size_t)b * SS + q0 + col) * QS + h * HD + quad * 8;
#pragma unroll
    for (int mm = 0; mm < 2; mm++) {
      float4 x0 = *(const float4*)(qp + mm * 32);
      float4 x1 = *(const float4*)(qp + mm * 32 + 4);
      v8s r;
      r[0] = (short)f2bf(x0.x * 0.125f); r[1] = (short)f2bf(x0.y * 0.125f);
      r[2] = (short)f2bf(x0.z * 0.125f); r[3] = (short)f2bf(x0.w * 0.125f);
      r[4] = (short)f2bf(x1.x * 0.125f); r[5] = (short)f2bf(x1.y * 0.125f);
      r[6] = (short)f2bf(x1.z * 0.125f); r[7] = (short)f2bf(x1.w * 0.125f);
      aq[mm] = r;
    }
  }
  float m_run[4] = {-1e30f, -1e30f, -1e30f, -1e30f};
  float l_run[4] = {0.f, 0.f, 0.f, 0.f};
  v4f accO[4] = {};
  const int kb_last = (q0 + 15) / 32;
  for (int kb = 0; kb <= kb_last; kb++) {
    const int off0 = q0 - kb * 32;       // >= 0 by construction
    const int off1 = off0 - 16;          // may be -16 (skip sub-tile 1)
    const bool do1 = (off1 > -16);
    // ---- scores ----
    v4f S0 = {}, S1 = {};
#pragma unroll
    for (int mm = 0; mm < 2; mm++) {
      int key0 = kb * 32 + col;
      v8s bk = *(const v8s*)(Ks + key0 * 64 + (((mm << 2) + quad) ^ (key0 & 7)) * 8);
      S0 = __builtin_amdgcn_mfma_f32_16x16x32_bf16(aq[mm], bk, S0, 0, 0, 0);
    }
    if (do1) {
#pragma unroll
      for (int mm = 0; mm < 2; mm++) {
        int key1 = kb * 32 + 16 + col;
        v8s bk = *(const v8s*)(Ks + key1 * 64 + (((mm << 2) + quad) ^ (key1 & 7)) * 8);
        S1 = __builtin_amdgcn_mfma_f32_16x16x32_bf16(aq[mm], bk, S1, 0, 0, 0);
      }
    }
    // ---- online softmax per query row (row = quad*4 + r) ----
    float alpha_r[4];
#pragma unroll
    for (int r = 0; r < 4; r++) {
      int row = quad * 4 + r;
      float s0 = (off0 >= 16 || col <= row + off0) ? S0[r] : -1e30f;
      float s1 = (do1 && (off1 >= 16 || col <= row + off1)) ? S1[r] : -1e30f;
      float mr = fmaxf(s0, s1);
      mr = fmaxf(mr, __shfl_xor(mr, 1));
      mr = fmaxf(mr, __shfl_xor(mr, 2));
      mr = fmaxf(mr, __shfl_xor(mr, 4));
      mr = fmaxf(mr, __shfl_xor(mr, 8));
      float mnew = fmaxf(m_run[r], mr);
      float alpha = expf(m_run[r] - mnew);
      float p0 = expf(s0 - mnew);
      float p1 = expf(s1 - mnew);
      Pw[row * PSTR + col] = f2bf(p0);
      Pw[row * PSTR + 16 + col] = f2bf(p1);
      float ls = p0 + p1;
      ls += __shfl_xor(ls, 1);
      ls += __shfl_xor(ls, 2);
      ls += __shfl_xor(ls, 4);
      ls += __shfl_xor(ls, 8);
      l_run[r] = l_run[r] * alpha + ls;
      m_run[r] = mnew;
      alpha_r[r] = alpha;
    }
#pragma unroll
    for (int c = 0; c < 4; c++)
#pragma unroll
      for (int r = 0; r < 4; r++) accO[c][r] *= alpha_r[r];
    // ---- PV: A = P[16q x 32k] (A-layout from LDS), B = Vt d-chunks ----
    v8s ap = *(const v8s*)(Pw + col * PSTR + quad * 8);
#pragma unroll
    for (int c = 0; c < 4; c++) {
      v8s bv = *(const v8s*)(Vt + (c * 16 + col) * VSTR + kb * 32 + quad * 8);
      accO[c] = __builtin_amdgcn_mfma_f32_16x16x32_bf16(ap, bv, accO[c], 0, 0, 0);
    }
  }
  // ---- epilogue ----
#pragma unroll
  for (int r = 0; r < 4; r++) {
    float inv = 1.f / l_run[r];
    int q = q0 + quad * 4 + r;
#pragma unroll
    for (int c = 0; c < 4; c++) {
      int d = c * 16 + col;
      o[((size_t)b * SS + q) * DD + h * HD + d] = f2bf(accO[c][r] * inv);
    }
  }
}

// ---------------- silu(gate)*up from fused [1024][4096] f32, writes bf16 [1024][2048] ----------------
__global__ __launch_bounds__(256) void silu_mul_kernel(const float* __restrict__ gu, unsigned short* __restrict__ out,
                                                       int n) {
  int i = blockIdx.x * 256 + threadIdx.x;
  if (i >= n) return;
  int m = i >> 11, j = i & 2047;
  float g = gu[(size_t)m * 4096 + j];
  float u = gu[(size_t)m * 4096 + 2048 + j];
  float s = g / (1.f + expf(-g));
  out[i] = f2bf(s * u);
}

// ---------------- context conv + softplus baseline ----------------
__global__ __launch_bounds__(256) void combine_kernel(float* __restrict__ logits, const float* __restrict__ c,
                                                      const float* __restrict__ conv_w, float* __restrict__ acc,
                                                      long total) {
  float cw = conv_w[0];
  float coef[FCS];  // coef[d-1] for offset d = 1..8 -> kernel[8-d] = exp(-cw*(8-d))
#pragma unroll
  for (int d = 1; d <= FCS; d++) coef[d - 1] = expf(-cw * (float)(FCS - d));
  float lsum = 0.f;
  long stride = (long)gridDim.x * 256;
  for (long idx = (long)blockIdx.x * 256 + threadIdx.x; idx < total; idx += stride) {
    float cv = c[idx];
    lsum += softplusf(cv);
    long bs = idx / VV;
    int s = (int)(bs % SS);
    float ctx = 0.f;
    int dmax = s < FCS ? s : FCS;
    for (int d = 1; d <= dmax; d++) ctx += coef[d - 1] * c[idx - (long)d * VV];
    logits[idx] += ctx;
  }
  __shared__ float rbuf[256];
  rbuf[threadIdx.x] = lsum; __syncthreads();
  for (int off = 128; off > 0; off >>= 1) {
    if (threadIdx.x < off) rbuf[threadIdx.x] += rbuf[threadIdx.x + off];
    __syncthreads();
  }
  if (threadIdx.x == 0) atomicAdd(acc + 2, rbuf[0]);
}

// ---------------- context-loss corrections (one thread per s) ----------------
__global__ __launch_bounds__(256) void corrections_kernel(const int* __restrict__ y, const float* __restrict__ c,
                                                          float* __restrict__ acc) {
  int s = blockIdx.x * 256 + threadIdx.x;
  if (s >= SS) return;
  const int YW = SS + FCS - 1;
  int w[2][FCS];
  for (int b = 0; b < 2; b++)
    for (int j = 0; j < FCS; j++) {
      int t = ((s - (FCS - 1) + j) % SS + SS) % SS;
      w[b][j] = y[b * YW + (FCS - 1) + t];
    }
  const float* c0 = c + (size_t)s * VV;
  const float* c1 = c + ((size_t)SS + s) * VV;
  float corr = 0.f;
  for (int b = 0; b < 2; b++) {
    const float* cb = b ? c1 : c0;
    for (int j = 0; j < FCS; j++) {
      int vv = w[b][j];
      bool seen = false;
      for (int p = 0; p < j; p++) if (w[b][p] == vv) { seen = true; break; }
      if (!seen) corr -= cb[vv];
    }
  }
  auto cnt = [&](int b, int vv) { int n = 0; for (int j = 0; j < FCS; j++) n += (w[b][j] == vv); return n; };
  auto inw = [&](int b, int vv) { for (int j = 0; j < FCS; j++) if (w[b][j] == vv) return true; return false; };
  for (int j = 0; j < FCS; j++) {
    int vv = w[0][j];
    bool first = true;
    for (int p = 0; p < j; p++) if (w[0][p] == vv) { first = false; break; }
    if (!first) continue;
    if (cnt(0, vv) > 1 || cnt(1, vv) > 1) {
      float b0 = softplusf(-c0[vv]);
      float b1 = inw(1, vv) ? softplusf(-c1[vv]) : softplusf(c1[vv]);
      corr += 0.5f * (b0 + b1);
    }
  }
  for (int j = 0; j < FCS; j++) {
    int vv = w[1][j];
    bool first = true;
    for (int p = 0; p < j; p++) if (w[1][p] == vv) { first = false; break; }
    if (!first) continue;
    if (inw(0, vv)) continue;
    if (cnt(1, vv) > 1) {
      float b0 = softplusf(c0[vv]);
      float b1 = softplusf(-c1[vv]);
      corr += 0.5f * (b0 + b1);
    }
  }
  atomicAdd(acc + 2, corr);
}

// ---------------- per-row NLL (one block per (b,s)) ----------------
__global__ __launch_bounds__(256) void row_loss_kernel(const float* __restrict__ logits, const int* __restrict__ y,
                                                       float* __restrict__ acc) {
  int row = blockIdx.x;  // b*S+s
  int b = row / SS, s = row % SS;
  const float* lp = logits + (size_t)row * VV;
  __shared__ float rbuf[256];
  int tid = threadIdx.x;
  float lm = -INFINITY;
  for (int vv = tid; vv < VV; vv += 256) lm = fmaxf(lm, lp[vv]);
  rbuf[tid] = lm; __syncthreads();
  for (int off = 128; off > 0; off >>= 1) {
    if (tid < off) rbuf[tid] = fmaxf(rbuf[tid], rbuf[tid + off]);
    __syncthreads();
  }
  float mx = rbuf[0];
  __syncthreads();
  float ls = 0.f;
  for (int vv = tid; vv < VV; vv += 256) ls += expf(lp[vv] - mx);
  rbuf[tid] = ls; __syncthreads();
  for (int off = 128; off > 0; off >>= 1) {
    if (tid < off) rbuf[tid] += rbuf[tid + off];
    __syncthreads();
  }
  if (tid == 0) {
    int yt = y[b * (SS + FCS - 1) + s];
    if (yt != -1) {
      float nll = (logf(rbuf[0]) + mx) - lp[yt];
      atomicAdd(acc + 0, nll);
      atomicAdd(acc + 1, 1.0f);
    }
  }
}

__global__ void finalize_kernel(float* __restrict__ out_scalars, const float* __restrict__ acc) {
  out_scalars[0] = acc[0] / fmaxf(acc[1], 1.0f);
  out_scalars[1] = acc[2] / (float)((long)BB * SS * VV);
}

extern "C" void kernel_launch(void* const* d_in, const int* in_sizes, int n_in,
                              void* d_out, int out_size, void* d_ws, size_t ws_size,
                              hipStream_t stream) {
  const int* x = (const int*)d_in[0];
  const int* y = (const int*)d_in[1];
  const float* emb = (const float*)d_in[2];
  const float* wq = (const float*)d_in[3];
  const float* wk = (const float*)d_in[4];
  const float* wv = (const float*)d_in[5];
  const float* wo = (const float*)d_in[6];
  const float* w1 = (const float*)d_in[7];
  const float* w2 = (const float*)d_in[8];
  const float* w3 = (const float*)d_in[9];
  const float* attn_norm = (const float*)d_in[10];
  const float* ffn_norm = (const float*)d_in[11];
  const float* out_norm = (const float*)d_in[12];
  const float* w_out = (const float*)d_in[13];
  const float* w_ctx = (const float*)d_in[14];
  const float* conv_w = (const float*)d_in[15];
  float* out = (float*)d_out;

  // ---- workspace carve (bytes, 256-aligned) ----
  char* ws = (char*)d_ws;
  size_t off = 0;
  auto carve = [&](size_t bytes) { char* p = ws + off; off += (bytes + 255) & ~(size_t)255; return p; };
  float* h    = (float*)carve((size_t)BB * SS * DD * 4);        // 3.1 MB
  float* qkv  = (float*)carve((size_t)BB * SS * QS * 4);        // 9.4 MB
  float* gu   = (float*)carve((size_t)BB * SS * 4096 * 4);      // 16.8 MB
  unsigned short* a16  = (unsigned short*)carve((size_t)BB * SS * DD * 2);
  unsigned short* ob16 = (unsigned short*)carve((size_t)BB * SS * DD * 2);
  unsigned short* gu16 = (unsigned short*)carve((size_t)BB * SS * FF * 2);
  float* c    = (float*)carve((size_t)BB * SS * VV * 4);        // 131 MB
  unsigned short* wbuf = (unsigned short*)carve((size_t)LL * (QS * DD + 4096 * DD + DD * DD + DD * FF) * 2);  // 56.6 MB
  float* acc  = (float*)carve(64);

  unsigned short* wqkv16 = wbuf;                                    // [L][2304][768]
  unsigned short* w1316  = wqkv16 + (size_t)LL * QS * DD;           // [L][4096][768]
  unsigned short* wo16   = w1316 + (size_t)LL * 4096 * DD;          // [L][768][768]
  unsigned short* w216   = wo16 + (size_t)LL * DD * DD;             // [L][768][2048]
  unsigned short* whead16 = wbuf;                                   // reused for w_out / w_ctx (49.2 MB <= 56.6)

  hipMemsetAsync(acc, 0, 16 * sizeof(float), stream);

  const int ROWS = BB * SS;  // 1024
  const long DD2 = (long)DD * DD, FD = (long)FF * DD;
  auto cvtgrid = [](long n) { return (int)((n / 4 + 255) / 256); };

  // ---- convert layer weights to bf16 (fused layouts) ----
  for (int l = 0; l < LL; l++) {
    cvt4_kernel<<<cvtgrid(DD2), 256, 0, stream>>>(wq + l * DD2, wqkv16 + (size_t)l * QS * DD + 0 * DD2, DD2);
    cvt4_kernel<<<cvtgrid(DD2), 256, 0, stream>>>(wk + l * DD2, wqkv16 + (size_t)l * QS * DD + 1 * DD2, DD2);
    cvt4_kernel<<<cvtgrid(DD2), 256, 0, stream>>>(wv + l * DD2, wqkv16 + (size_t)l * QS * DD + 2 * DD2, DD2);
    cvt4_kernel<<<cvtgrid(FD), 256, 0, stream>>>(w1 + l * FD, w1316 + (size_t)l * 4096 * DD, FD);
    cvt4_kernel<<<cvtgrid(FD), 256, 0, stream>>>(w3 + l * FD, w1316 + (size_t)l * 4096 * DD + (size_t)2048 * DD, FD);
    cvt4_kernel<<<cvtgrid(DD2), 256, 0, stream>>>(wo + l * DD2, wo16 + (size_t)l * DD2, DD2);
    cvt4_kernel<<<cvtgrid(FD), 256, 0, stream>>>(w2 + l * FD, w216 + (size_t)l * FD, FD);
  }

  // ---- embed ----
  embed_kernel<<<((int)(BB * SS * DD) + 255) / 256, 256, 0, stream>>>(x, emb, h, BB * SS * DD, DD);

  // ---- layers ----
  for (int l = 0; l < LL; l++) {
    rmsnorm_kernel<<<ROWS, 256, 0, stream>>>(h, attn_norm + l * DD, a16, DD);
    gemm_bf16<0><<<dim3(QS / 128, ROWS / 128), 256, 0, stream>>>(a16, wqkv16 + (size_t)l * QS * DD, qkv, ROWS, QS, DD);
    int rope_total = BB * SS * HH * 32;
    rope_kernel<<<(rope_total + 255) / 256, 256, 0, stream>>>(qkv, rope_total);
    attn_mfma_kernel<<<dim3(SS / 64, HH, BB), 256, 0, stream>>>(qkv, ob16);
    gemm_bf16<1><<<dim3(DD / 128, ROWS / 128), 256, 0, stream>>>(ob16, wo16 + (size_t)l * DD2, h, ROWS, DD, DD);

    rmsnorm_kernel<<<ROWS, 256, 0, stream>>>(h, ffn_norm + l * DD, a16, DD);
    gemm_bf16<0><<<dim3(4096 / 128, ROWS / 128), 256, 0, stream>>>(a16, w1316 + (size_t)l * 4096 * DD, gu, ROWS, 4096, DD);
    silu_mul_kernel<<<(ROWS * FF + 255) / 256, 256, 0, stream>>>(gu, gu16, ROWS * FF);
    gemm_bf16<1><<<dim3(DD / 128, ROWS / 128), 256, 0, stream>>>(gu16, w216 + (size_t)l * FD, h, ROWS, DD, FF);
  }

  // ---- final norm + heads (lazy head-weight conversion into reused wbuf) ----
  rmsnorm_kernel<<<ROWS, 256, 0, stream>>>(h, out_norm, a16, DD);
  const long HV = (long)VV * DD;
  cvt4_kernel<<<cvtgrid(HV), 256, 0, stream>>>(w_out, whead16, HV);
  gemm_bf16<0><<<dim3(VV / 128, ROWS / 128), 256, 0, stream>>>(a16, whead16, out, ROWS, VV, DD);
  cvt4_kernel<<<cvtgrid(HV), 256, 0, stream>>>(w_ctx, whead16, HV);
  gemm_bf16<0><<<dim3(VV / 128, ROWS / 128), 256, 0, stream>>>(a16, whead16, c, ROWS, VV, DD);

  // ---- losses ----
  const long CSZ = (long)BB * SS * VV;
  combine_kernel<<<16384, 256, 0, stream>>>(out, c, conv_w, acc, CSZ);
  corrections_kernel<<<2, 256, 0, stream>>>(y, c, acc);
  row_loss_kernel<<<ROWS, 256, 0, stream>>>(out, y, acc);
  finalize_kernel<<<1, 1, 0, stream>>>(out + CSZ, acc);
}